// Round 6
// baseline (1088.852 us; speedup 1.0000x reference)
//
#include <hip/hip_runtime.h>
#include <hip/hip_bf16.h>
#include <math.h>

// MoE forward: B=4 T=2048 C=1024 F=4096 E=8 K=2, CAPACITY=2048, fp32 in/out.
// Pipeline: cvt(x->bf16, W1->bf16 [F][C]) -> gate(top2) -> FCFS scan (exact
// slot-order capacity) -> GEMM1 (gather-A, gelu, bf16 H) -> cvt W2 -> GEMM2
// (epilogue scatters w*(acc+b2) into out via atomicAdd; exactly <=2
// commutative adds per element -> deterministic) ; aux loss scalar at out[N*C].
// Workspace peak ~208.3 MiB (W2t converted after GEMM1 over dead xb/W1t).

#define DEV __device__ __forceinline__

typedef __attribute__((ext_vector_type(4))) float f32x4;
typedef __attribute__((ext_vector_type(8))) short bf16x8;

constexpr int B_ = 4, T_ = 2048, C_ = 1024, F_ = 4096, E_ = 8, TOPK_ = 2;
constexpr int N_ = B_ * T_;       // 8192 tokens
constexpr int S_ = N_ * TOPK_;    // 16384 slots
constexpr int CAP_ = 2048;

#define GLOAD16(G, L)                                              \
  __builtin_amdgcn_global_load_lds(                                \
      (const __attribute__((address_space(1))) void*)(G),          \
      (__attribute__((address_space(3))) void*)(L), 16, 0, 0)

DEV float gelu_tanh(float x) {
  float x3 = x * x * x;
  float u = 0.7978845608028654f * (x + 0.044715f * x3);
  return 0.5f * x * (1.0f + tanhf(u));
}

// ---------------- conversion kernels ----------------

__global__ __launch_bounds__(256) void cvt_x_kernel(
    const float* __restrict__ in, __hip_bfloat16* __restrict__ out, int n4) {
  int i = blockIdx.x * 256 + threadIdx.x;
  if (i >= n4) return;
  float4 v = ((const float4*)in)[i];
  __hip_bfloat16 o[4] = {__float2bfloat16(v.x), __float2bfloat16(v.y),
                         __float2bfloat16(v.z), __float2bfloat16(v.w)};
  *(uint2*)(out + (size_t)i * 4) = *(uint2*)o;
}

// in: fp32 [E][R][S] -> out: bf16 [E][S][R]
__global__ __launch_bounds__(256) void transpose_cvt_kernel(
    const float* __restrict__ in, __hip_bfloat16* __restrict__ out, int R, int S) {
  __shared__ float tile[32][33];
  int e = blockIdx.z;
  int s0 = blockIdx.x * 32;
  int r0 = blockIdx.y * 32;
  int tx = threadIdx.x & 31;
  int ty = threadIdx.x >> 5;  // 0..7
  const float* ip = in + (size_t)e * R * S;
  __hip_bfloat16* op = out + (size_t)e * R * S;
#pragma unroll
  for (int i = 0; i < 32; i += 8)
    tile[ty + i][tx] = ip[(size_t)(r0 + ty + i) * S + s0 + tx];
  __syncthreads();
#pragma unroll
  for (int i = 0; i < 32; i += 8)
    op[(size_t)(s0 + ty + i) * R + r0 + tx] = __float2bfloat16(tile[tx][ty + i]);
}

// ---------------- gating ----------------

__global__ __launch_bounds__(256) void gate_kernel(
    const float* __restrict__ x, const float* __restrict__ wg,
    const float* __restrict__ bg, int* __restrict__ slot_e,
    float* __restrict__ slot_w, float* __restrict__ probs_sum) {
  int lane = threadIdx.x & 63;
  int wv = threadIdx.x >> 6;
  int wid = blockIdx.x * 4 + wv;  // 0..1023, 8 tokens each
  float psum[E_];
#pragma unroll
  for (int e = 0; e < E_; ++e) psum[e] = 0.f;

  for (int ti = 0; ti < 8; ++ti) {
    int t = wid * 8 + ti;
    const float* xr = x + (size_t)t * C_;
    float acc[E_];
#pragma unroll
    for (int e = 0; e < E_; ++e) acc[e] = 0.f;
    for (int c = lane; c < C_; c += 64) {
      float xv = xr[c];
      const float* wr = wg + (size_t)c * E_;
#pragma unroll
      for (int e = 0; e < E_; ++e) acc[e] += xv * wr[e];
    }
#pragma unroll
    for (int e = 0; e < E_; ++e) {
#pragma unroll
      for (int off = 32; off >= 1; off >>= 1)
        acc[e] += __shfl_xor(acc[e], off, 64);
    }
    if (lane == 0) {
      float lg[E_], p[E_];
      float mx = -1e30f;
#pragma unroll
      for (int e = 0; e < E_; ++e) { lg[e] = acc[e] + bg[e]; mx = fmaxf(mx, lg[e]); }
      float s = 0.f;
#pragma unroll
      for (int e = 0; e < E_; ++e) { p[e] = expf(lg[e] - mx); s += p[e]; }
      float inv = 1.f / s;
#pragma unroll
      for (int e = 0; e < E_; ++e) { p[e] *= inv; psum[e] += p[e]; }
      // top-2, ties -> lower index first (matches lax.top_k)
      int i1 = 0; float p1 = p[0];
#pragma unroll
      for (int e = 1; e < E_; ++e) if (p[e] > p1) { p1 = p[e]; i1 = e; }
      int i2 = -1; float p2 = -1.f;
#pragma unroll
      for (int e = 0; e < E_; ++e) if (e != i1 && p[e] > p2) { p2 = p[e]; i2 = e; }
      float wden = 1.f / (p1 + p2 + 1e-9f);
      slot_e[2 * t] = i1;     slot_w[2 * t] = p1 * wden;
      slot_e[2 * t + 1] = i2; slot_w[2 * t + 1] = p2 * wden;
    }
  }
  if (lane == 0) {
#pragma unroll
    for (int e = 0; e < E_; ++e) atomicAdd(&probs_sum[e], psum[e]);
  }
}

// ---------------- FCFS capacity scan (single block, exact slot order) -------

__global__ __launch_bounds__(256) void scan_kernel(
    const int* __restrict__ slot_e, const float* __restrict__ slot_w,
    int* __restrict__ idx_list, float* __restrict__ w_list,
    const float* __restrict__ probs_sum, float* __restrict__ aux_out) {
  __shared__ int sc[256][E_];
  int tid = threadIdx.x;
  int s0 = tid * 64;
  int cnt[E_];
#pragma unroll
  for (int e = 0; e < E_; ++e) cnt[e] = 0;
  for (int j = 0; j < 64; ++j) cnt[slot_e[s0 + j]]++;
#pragma unroll
  for (int e = 0; e < E_; ++e) sc[tid][e] = cnt[e];
  __syncthreads();
  for (int off = 1; off < 256; off <<= 1) {
    int v[E_];
    bool act = (tid >= off);
    if (act) {
#pragma unroll
      for (int e = 0; e < E_; ++e) v[e] = sc[tid - off][e];
    }
    __syncthreads();
    if (act) {
#pragma unroll
      for (int e = 0; e < E_; ++e) sc[tid][e] += v[e];
    }
    __syncthreads();
  }
  int base[E_];
#pragma unroll
  for (int e = 0; e < E_; ++e) base[e] = tid ? sc[tid - 1][e] : 0;
  for (int j = 0; j < 64; ++j) {
    int s = s0 + j;
    int e = slot_e[s];
    int p = base[e]++;
    if (p < CAP_) {
      idx_list[e * CAP_ + p] = s >> 1;       // token index
      w_list[e * CAP_ + p] = slot_w[s];      // combine weight
    }
  }
  if (tid == 0) {
    float fe[E_], fa[E_], fs = 0.f, ls = 0.f;
#pragma unroll
    for (int e = 0; e < E_; ++e) {
      fe[e] = probs_sum[e] / (float)N_;
      fs += fe[e];
      int tot = sc[255][e];
      fa[e] = (float)(tot < CAP_ ? tot : CAP_);
      ls += fa[e];
    }
    float i1 = 1.f / (fs + 1e-9f), i2 = 1.f / (ls + 1e-9f);
    float a = 0.f;
#pragma unroll
    for (int e = 0; e < E_; ++e) {
      float d = fe[e] * i1 - fa[e] * i2;
      a += d * d;
    }
    aux_out[0] = 0.01f * a / (float)E_;
  }
}

// ---------------- MFMA GEMM (m97 structure: 128x128 tile, BK=32, gload_lds) -
// EPI 0: gelu(acc+bias) -> bf16 H[e][row][col]
// EPI 1: scatter w_list[e][row] * (acc+bias) -> atomicAdd out[idx_list[e][row]][col]

template <int EPI, bool GATHER>
__global__ __launch_bounds__(256) void gemm_tile(
    const __hip_bfloat16* __restrict__ Aall,  // GATHER: xb [N][K]; else Hb rows
    const __hip_bfloat16* __restrict__ Ball,  // [E][Ndim][Kdim] (k contiguous)
    const int* __restrict__ idxl,             // [E][CAP]
    const float* __restrict__ wl,             // [E][CAP] (EPI==1)
    const float* __restrict__ bias,           // [E][Ndim]
    void* __restrict__ Cout,                  // EPI0: bf16 [E][CAP][Ndim]; EPI1: f32 [N][C]
    const __hip_bfloat16* __restrict__ zrow,  // >= Kdim zeros
    int Ndim, int Kdim) {
  const int e = blockIdx.z;
  const int row0 = blockIdx.y * 128;
  const int col0 = blockIdx.x * 128;
  const int tid = threadIdx.x;
  const int lane = tid & 63;
  const int wv = tid >> 6;
  const int wm = wv >> 1, wn = wv & 1;

  __shared__ __align__(16) __hip_bfloat16 As[128 * 32];
  __shared__ __align__(16) __hip_bfloat16 Bs[128 * 32];

  // staging: thread covers (row = tid>>2, kblk = (tid&3)*8) and +64 rows
  const int rA0 = tid >> 2, kA0 = (tid & 3) * 8;
  const int rA1 = rA0 + 64;

  const __hip_bfloat16 *rowA0, *rowA1;
  if (GATHER) {
    int tok0 = idxl[e * CAP_ + row0 + rA0];
    int tok1 = idxl[e * CAP_ + row0 + rA1];
    rowA0 = (tok0 >= 0) ? Aall + (size_t)tok0 * Kdim : zrow;
    rowA1 = (tok1 >= 0) ? Aall + (size_t)tok1 * Kdim : zrow;
  } else {
    rowA0 = Aall + ((size_t)e * CAP_ + row0 + rA0) * Kdim;
    rowA1 = Aall + ((size_t)e * CAP_ + row0 + rA1) * Kdim;
  }
  const __hip_bfloat16* Be = Ball + (size_t)e * Ndim * Kdim;
  const __hip_bfloat16* rowB0 = Be + (size_t)(col0 + rA0) * Kdim;
  const __hip_bfloat16* rowB1 = Be + (size_t)(col0 + rA1) * Kdim;

  // wave-uniform LDS bases (hardware writes base + lane*16B; lane*8 bf16
  // == (lane>>2)*32 + (lane&3)*8, i.e. exactly rows wv*16..+15 of [128][32])
  __hip_bfloat16* ldsA0 = As + (size_t)(wv * 64) * 8;
  __hip_bfloat16* ldsA1 = As + (size_t)(256 + wv * 64) * 8;
  __hip_bfloat16* ldsB0 = Bs + (size_t)(wv * 64) * 8;
  __hip_bfloat16* ldsB1 = Bs + (size_t)(256 + wv * 64) * 8;

  f32x4 acc[4][4];
#pragma unroll
  for (int m = 0; m < 4; ++m)
#pragma unroll
    for (int n = 0; n < 4; ++n) acc[m][n] = (f32x4){0.f, 0.f, 0.f, 0.f};

  const int rsel = lane & 15;
  const int ksel = (lane >> 4) * 8;

  for (int k0 = 0; k0 < Kdim; k0 += 32) {
    GLOAD16(rowA0 + k0 + kA0, ldsA0);
    GLOAD16(rowA1 + k0 + kA0, ldsA1);
    GLOAD16(rowB0 + k0 + kA0, ldsB0);
    GLOAD16(rowB1 + k0 + kA0, ldsB1);
    __syncthreads();  // compiler drains vmcnt before barrier

    bf16x8 af[4], bfv[4];
#pragma unroll
    for (int m = 0; m < 4; ++m)
      af[m] = *(const bf16x8*)(As + (wm * 64 + m * 16 + rsel) * 32 + ksel);
#pragma unroll
    for (int n = 0; n < 4; ++n)
      bfv[n] = *(const bf16x8*)(Bs + (wn * 64 + n * 16 + rsel) * 32 + ksel);
#pragma unroll
    for (int m = 0; m < 4; ++m)
#pragma unroll
      for (int n = 0; n < 4; ++n)
        acc[m][n] = __builtin_amdgcn_mfma_f32_16x16x32_bf16(af[m], bfv[n],
                                                            acc[m][n], 0, 0, 0);
    __syncthreads();
  }

  // epilogue: D row = (lane>>4)*4 + j (+16m), col = lane&15 (+16n)
  const float* brow = bias + (size_t)e * Ndim;
  const int orow0 = row0 + wm * 64 + (lane >> 4) * 4;
  const int ocol0 = col0 + wn * 64 + rsel;
  if (EPI == 0) {
    __hip_bfloat16* H = (__hip_bfloat16*)Cout + (size_t)e * CAP_ * Ndim;
#pragma unroll
    for (int m = 0; m < 4; ++m) {
#pragma unroll
      for (int n = 0; n < 4; ++n) {
        int cc = ocol0 + n * 16;
        float bv = brow[cc];
#pragma unroll
        for (int j = 0; j < 4; ++j) {
          int rr = orow0 + m * 16 + j;
          H[(size_t)rr * Ndim + cc] = __float2bfloat16(gelu_tanh(acc[m][n][j] + bv));
        }
      }
    }
  } else {
    float* out = (float*)Cout;
#pragma unroll
    for (int m = 0; m < 4; ++m) {
#pragma unroll
      for (int j = 0; j < 4; ++j) {
        int rr = orow0 + m * 16 + j;
        int t = idxl[e * CAP_ + rr];
        if (t < 0) continue;
        float w = wl[e * CAP_ + rr];
#pragma unroll
        for (int n = 0; n < 4; ++n) {
          int cc = ocol0 + n * 16;
          unsafeAtomicAdd(&out[(size_t)t * C_ + cc], w * (acc[m][n][j] + brow[cc]));
        }
      }
    }
  }
}

// ---------------- launch ----------------

extern "C" void kernel_launch(void* const* d_in, const int* in_sizes, int n_in,
                              void* d_out, int out_size, void* d_ws,
                              size_t ws_size, hipStream_t stream) {
  (void)in_sizes; (void)n_in; (void)out_size; (void)ws_size;
  const float* x = (const float*)d_in[0];
  const float* w_gate = (const float*)d_in[1];
  const float* b_gate = (const float*)d_in[2];
  const float* W1 = (const float*)d_in[3];
  const float* b1 = (const float*)d_in[4];
  const float* W2 = (const float*)d_in[5];
  const float* b2 = (const float*)d_in[6];
  float* out = (float*)d_out;

  // Workspace layout (peak ~208.3 MiB):
  //   [0,16)    xb   bf16 [N][C]        (dead after GEMM1)
  //   [16,80)   W1t  bf16 [E][F][C]     (dead after GEMM1)
  //   [0,64)    W2t  bf16 [E][C][F]     (converted after GEMM1, over xb/W1t)
  //   [80,208)  Hb   bf16 [E][CAP][F]
  //   [208,...) meta
  char* p = (char*)d_ws;
  __hip_bfloat16* xb = (__hip_bfloat16*)p;
  __hip_bfloat16* W1t = (__hip_bfloat16*)(p + ((size_t)16 << 20));
  __hip_bfloat16* W2t = (__hip_bfloat16*)p;
  __hip_bfloat16* Hb = (__hip_bfloat16*)(p + ((size_t)80 << 20));
  char* meta = p + ((size_t)208 << 20);
  int* slot_e = (int*)meta;                       // 64 KiB
  float* slot_w = (float*)(meta + (64 << 10));    // 64 KiB
  int* idx_list = (int*)(meta + (128 << 10));     // 64 KiB
  float* w_list = (float*)(meta + (192 << 10));   // 64 KiB
  float* probs_sum = (float*)(meta + (256 << 10));
  __hip_bfloat16* zrow = (__hip_bfloat16*)(meta + (260 << 10));  // 16 KiB zeros

  hipMemsetAsync(idx_list, 0xFF, E_ * CAP_ * sizeof(int), stream);
  hipMemsetAsync(probs_sum, 0, E_ * sizeof(float), stream);
  hipMemsetAsync(zrow, 0, 16 << 10, stream);
  hipMemsetAsync(out, 0, (size_t)N_ * C_ * sizeof(float), stream);

  cvt_x_kernel<<<(N_ * C_ / 4 + 255) / 256, 256, 0, stream>>>(x, xb, N_ * C_ / 4);
  transpose_cvt_kernel<<<dim3(F_ / 32, C_ / 32, E_), 256, 0, stream>>>(W1, W1t, C_, F_);
  gate_kernel<<<N_ / 32, 256, 0, stream>>>(x, w_gate, b_gate, slot_e, slot_w, probs_sum);
  scan_kernel<<<1, 256, 0, stream>>>(slot_e, slot_w, idx_list, w_list, probs_sum,
                                     out + (size_t)N_ * C_);
  gemm_tile<0, true><<<dim3(F_ / 128, CAP_ / 128, E_), 256, 0, stream>>>(
      xb, W1t, idx_list, nullptr, b1, Hb, zrow, F_, C_);
  transpose_cvt_kernel<<<dim3(C_ / 32, F_ / 32, E_), 256, 0, stream>>>(W2, W2t, F_, C_);
  gemm_tile<1, false><<<dim3(C_ / 128, CAP_ / 128, E_), 256, 0, stream>>>(
      Hb, W2t, idx_list, w_list, b2, out, zrow, C_, F_);
}

// Round 7
// 977.887 us; speedup vs baseline: 1.1135x; 1.1135x over previous
//
#include <hip/hip_runtime.h>
#include <hip/hip_bf16.h>
#include <math.h>

// MoE forward: B=4 T=2048 C=1024 F=4096 E=8 K=2, CAPACITY=2048, fp32 in/out.
// R6: GEMMs rebuilt as 256x256 tile / BK=64 / 8-wave / 4-phase (T2 swizzle +
// T3 pipelined stage + T5 setprio + T1 XCD chunking). Strict double-buffer:
// tile t+1 staged (8 global_load_lds) during tile t phase 0, one vmcnt(0)
// gate per K-tile. B-fragments register-cached across phases.

#define DEV __device__ __forceinline__

typedef __attribute__((ext_vector_type(4))) float f32x4;
typedef __attribute__((ext_vector_type(8))) short bf16x8;

constexpr int B_ = 4, T_ = 2048, C_ = 1024, F_ = 4096, E_ = 8, TOPK_ = 2;
constexpr int N_ = B_ * T_;       // 8192 tokens
constexpr int S_ = N_ * TOPK_;    // 16384 slots
constexpr int CAP_ = 2048;

#define GLOAD16(G, L)                                              \
  __builtin_amdgcn_global_load_lds(                                \
      (const __attribute__((address_space(1))) void*)(G),          \
      (__attribute__((address_space(3))) void*)(L), 16, 0, 0)

DEV float gelu_tanh(float x) {
  float x3 = x * x * x;
  float u = 0.7978845608028654f * (x + 0.044715f * x3);
  return 0.5f * x * (1.0f + tanhf(u));
}

// ---------------- conversion kernels ----------------

__global__ __launch_bounds__(256) void cvt_x_kernel(
    const float* __restrict__ in, __hip_bfloat16* __restrict__ out, int n4) {
  int i = blockIdx.x * 256 + threadIdx.x;
  if (i >= n4) return;
  float4 v = ((const float4*)in)[i];
  __hip_bfloat16 o[4] = {__float2bfloat16(v.x), __float2bfloat16(v.y),
                         __float2bfloat16(v.z), __float2bfloat16(v.w)};
  *(uint2*)(out + (size_t)i * 4) = *(uint2*)o;
}

// in: fp32 [E][R][S] -> out: bf16 [E][S][R]
__global__ __launch_bounds__(256) void transpose_cvt_kernel(
    const float* __restrict__ in, __hip_bfloat16* __restrict__ out, int R, int S) {
  __shared__ float tile[32][33];
  int e = blockIdx.z;
  int s0 = blockIdx.x * 32;
  int r0 = blockIdx.y * 32;
  int tx = threadIdx.x & 31;
  int ty = threadIdx.x >> 5;  // 0..7
  const float* ip = in + (size_t)e * R * S;
  __hip_bfloat16* op = out + (size_t)e * R * S;
#pragma unroll
  for (int i = 0; i < 32; i += 8)
    tile[ty + i][tx] = ip[(size_t)(r0 + ty + i) * S + s0 + tx];
  __syncthreads();
#pragma unroll
  for (int i = 0; i < 32; i += 8)
    op[(size_t)(s0 + ty + i) * R + r0 + tx] = __float2bfloat16(tile[tx][ty + i]);
}

// ---------------- gating ----------------

__global__ __launch_bounds__(256) void gate_kernel(
    const float* __restrict__ x, const float* __restrict__ wg,
    const float* __restrict__ bg, int* __restrict__ slot_e,
    float* __restrict__ slot_w, float* __restrict__ probs_sum) {
  int lane = threadIdx.x & 63;
  int wv = threadIdx.x >> 6;
  int wid = blockIdx.x * 4 + wv;  // 0..1023, 8 tokens each
  float psum[E_];
#pragma unroll
  for (int e = 0; e < E_; ++e) psum[e] = 0.f;

  for (int ti = 0; ti < 8; ++ti) {
    int t = wid * 8 + ti;
    const float* xr = x + (size_t)t * C_;
    float acc[E_];
#pragma unroll
    for (int e = 0; e < E_; ++e) acc[e] = 0.f;
    for (int c = lane; c < C_; c += 64) {
      float xv = xr[c];
      const float* wr = wg + (size_t)c * E_;
#pragma unroll
      for (int e = 0; e < E_; ++e) acc[e] += xv * wr[e];
    }
#pragma unroll
    for (int e = 0; e < E_; ++e) {
#pragma unroll
      for (int off = 32; off >= 1; off >>= 1)
        acc[e] += __shfl_xor(acc[e], off, 64);
    }
    if (lane == 0) {
      float lg[E_], p[E_];
      float mx = -1e30f;
#pragma unroll
      for (int e = 0; e < E_; ++e) { lg[e] = acc[e] + bg[e]; mx = fmaxf(mx, lg[e]); }
      float s = 0.f;
#pragma unroll
      for (int e = 0; e < E_; ++e) { p[e] = expf(lg[e] - mx); s += p[e]; }
      float inv = 1.f / s;
#pragma unroll
      for (int e = 0; e < E_; ++e) { p[e] *= inv; psum[e] += p[e]; }
      int i1 = 0; float p1 = p[0];
#pragma unroll
      for (int e = 1; e < E_; ++e) if (p[e] > p1) { p1 = p[e]; i1 = e; }
      int i2 = -1; float p2 = -1.f;
#pragma unroll
      for (int e = 0; e < E_; ++e) if (e != i1 && p[e] > p2) { p2 = p[e]; i2 = e; }
      float wden = 1.f / (p1 + p2 + 1e-9f);
      slot_e[2 * t] = i1;     slot_w[2 * t] = p1 * wden;
      slot_e[2 * t + 1] = i2; slot_w[2 * t + 1] = p2 * wden;
    }
  }
  if (lane == 0) {
#pragma unroll
    for (int e = 0; e < E_; ++e) atomicAdd(&probs_sum[e], psum[e]);
  }
}

// ---------------- FCFS capacity scan (single block, exact slot order) -------

__global__ __launch_bounds__(256) void scan_kernel(
    const int* __restrict__ slot_e, const float* __restrict__ slot_w,
    int* __restrict__ idx_list, float* __restrict__ w_list,
    const float* __restrict__ probs_sum, float* __restrict__ aux_out) {
  __shared__ int sc[256][E_];
  int tid = threadIdx.x;
  int s0 = tid * 64;
  int cnt[E_];
#pragma unroll
  for (int e = 0; e < E_; ++e) cnt[e] = 0;
  for (int j = 0; j < 64; ++j) cnt[slot_e[s0 + j]]++;
#pragma unroll
  for (int e = 0; e < E_; ++e) sc[tid][e] = cnt[e];
  __syncthreads();
  for (int off = 1; off < 256; off <<= 1) {
    int v[E_];
    bool act = (tid >= off);
    if (act) {
#pragma unroll
      for (int e = 0; e < E_; ++e) v[e] = sc[tid - off][e];
    }
    __syncthreads();
    if (act) {
#pragma unroll
      for (int e = 0; e < E_; ++e) sc[tid][e] += v[e];
    }
    __syncthreads();
  }
  int base[E_];
#pragma unroll
  for (int e = 0; e < E_; ++e) base[e] = tid ? sc[tid - 1][e] : 0;
  for (int j = 0; j < 64; ++j) {
    int s = s0 + j;
    int e = slot_e[s];
    int p = base[e]++;
    if (p < CAP_) {
      idx_list[e * CAP_ + p] = s >> 1;       // token index
      w_list[e * CAP_ + p] = slot_w[s];      // combine weight
    }
  }
  if (tid == 0) {
    float fe[E_], fa[E_], fs = 0.f, ls = 0.f;
#pragma unroll
    for (int e = 0; e < E_; ++e) {
      fe[e] = probs_sum[e] / (float)N_;
      fs += fe[e];
      int tot = sc[255][e];
      fa[e] = (float)(tot < CAP_ ? tot : CAP_);
      ls += fa[e];
    }
    float i1 = 1.f / (fs + 1e-9f), i2 = 1.f / (ls + 1e-9f);
    float a = 0.f;
#pragma unroll
    for (int e = 0; e < E_; ++e) {
      float d = fe[e] * i1 - fa[e] * i2;
      a += d * d;
    }
    aux_out[0] = 0.01f * a / (float)E_;
  }
}

// ---------------- 256x256 4-phase MFMA GEMM -------------------------------
// 512 threads = 8 waves (2M x 4N); per-wave C = 128x64 (acc[8][4] f32x4).
// LDS: 2 buf x (A[256][64] + B[256][64]) bf16 = 128 KiB, st_16x32 swizzle
// (byte ^= ((byte>>9)&1)<<5 : flip col-byte bit5 when row&4) applied on the
// pre-swizzled GLOBAL source (rule #21) and on every ds_read.
// Schedule per K-tile t: phase0 {ds_read B(8)+A(4); STAGE tile t+1 (8 gload);
// barrier; setprio; 16 MFMA; setprio; barrier}, phases1-3 {ds_read A(4);
// barrier; setprio; 16 MFMA; setprio; barrier}; then vmcnt(0)+barrier gate.
// EPI 0: gelu(acc+bias) -> bf16 H ; EPI 1: atomic scatter to out.

template <int EPI, bool GATHER>
__global__ __launch_bounds__(512, 2) void gemm256(
    const __hip_bfloat16* __restrict__ Aall,
    const __hip_bfloat16* __restrict__ Ball,
    const int* __restrict__ idxl,
    const float* __restrict__ wl,
    const float* __restrict__ bias,
    void* __restrict__ Cout,
    const __hip_bfloat16* __restrict__ zrow,
    int Ndim, int Kdim, int ncol) {
  __shared__ __align__(16) __hip_bfloat16 lds[2][2][256 * 64];  // 128 KiB

  // T1: bijective XCD swizzle (gridDim.x % 8 == 0); y innermost so the 8
  // row-blocks sharing a B col-panel are consecutive on one XCD.
  const int nwg = gridDim.x;
  const int wg = ((int)blockIdx.x & 7) * (nwg >> 3) + ((int)blockIdx.x >> 3);
  const int e = wg / (ncol * 8);
  const int rem = wg - e * (ncol * 8);
  const int x = rem >> 3, y = rem & 7;
  const int row0 = y * 256, col0 = x * 256;

  const int tid = threadIdx.x;
  const int lane = tid & 63;
  const int w = tid >> 6;           // 0..7
  const int wm = w >> 2, wn = w & 3;

  // ---- staging: 4 chunks x 64 rows each for A and B; thread covers
  // row r = c*64 + w*8 + (lane>>3), 16B at swizzled col-byte cb.
  const int cb = ((lane & 7) * 16) ^ ((lane >> 5) << 5);
  const int rch = w * 8 + (lane >> 3);
  const __hip_bfloat16* srcA[4];
  const __hip_bfloat16* srcB[4];
  const __hip_bfloat16* Be = Ball + (size_t)e * Ndim * Kdim;
#pragma unroll
  for (int c = 0; c < 4; ++c) {
    int r = c * 64 + rch;
    if (GATHER) {
      int tok = idxl[e * CAP_ + row0 + r];
      srcA[c] = ((tok >= 0) ? Aall + (size_t)tok * Kdim : zrow) + (cb >> 1);
    } else {
      srcA[c] = Aall + ((size_t)e * CAP_ + row0 + r) * Kdim + (cb >> 1);
    }
    srcB[c] = Be + (size_t)(col0 + r) * Kdim + (cb >> 1);
  }
  const int dstoff = w * 512;  // elems; + c*4096 per chunk (gload adds lane*16B)

  // ---- fragment read geometry (16x16x32: row=lane&15, k=(lane>>4)*8+i) ----
  const int sxor = (lane & 4) << 3;           // swizzle: 32 iff row&4
  const int rA = wm * 128 + (lane & 15);
  const int rB = wn * 64 + (lane & 15);
  const int kb = (lane >> 4) * 16;            // k-bytes within 32-k step

  f32x4 acc[8][4];
#pragma unroll
  for (int i = 0; i < 8; ++i)
#pragma unroll
    for (int j = 0; j < 4; ++j) acc[i][j] = (f32x4){0.f, 0.f, 0.f, 0.f};

  const int NT = Kdim >> 6;

#define STAGE_TILE(PAR, T)                                        \
  {                                                               \
    const int k0_ = (T) * 64;                                     \
    _Pragma("unroll") for (int c = 0; c < 4; ++c) {               \
      GLOAD16(srcA[c] + k0_, &lds[PAR][0][c * 4096 + dstoff]);    \
      GLOAD16(srcB[c] + k0_, &lds[PAR][1][c * 4096 + dstoff]);    \
    }                                                             \
  }

  STAGE_TILE(0, 0);
  asm volatile("s_waitcnt vmcnt(0)" ::: "memory");
  __builtin_amdgcn_sched_barrier(0);
  __builtin_amdgcn_s_barrier();
  __builtin_amdgcn_sched_barrier(0);

  for (int t = 0; t < NT; ++t) {
    const int par = t & 1;
    const char* baseA = (const char*)&lds[par][0][0];
    const char* baseB = (const char*)&lds[par][1][0];
    bf16x8 bfr[4][2];  // B-frags cached for all 4 phases
#pragma unroll
    for (int q = 0; q < 4; ++q) {
      if (q == 0) {
#pragma unroll
        for (int n = 0; n < 4; ++n)
#pragma unroll
          for (int ks = 0; ks < 2; ++ks)
            bfr[n][ks] = *(const bf16x8*)(
                baseB + ((((rB + n * 16) * 128) + ks * 64 + kb) ^ sxor));
      }
      bf16x8 af[2][2];
#pragma unroll
      for (int i = 0; i < 2; ++i)
#pragma unroll
        for (int ks = 0; ks < 2; ++ks)
          af[i][ks] = *(const bf16x8*)(
              baseA + ((((rA + (q * 2 + i) * 16) * 128) + ks * 64 + kb) ^ sxor));
      if (q == 0 && t + 1 < NT) STAGE_TILE(par ^ 1, t + 1);
      __builtin_amdgcn_s_barrier();
      __builtin_amdgcn_s_setprio(1);
#pragma unroll
      for (int ks = 0; ks < 2; ++ks)
#pragma unroll
        for (int i = 0; i < 2; ++i)
#pragma unroll
          for (int n = 0; n < 4; ++n)
            acc[q * 2 + i][n] = __builtin_amdgcn_mfma_f32_16x16x32_bf16(
                af[i][ks], bfr[n][ks], acc[q * 2 + i][n], 0, 0, 0);
      __builtin_amdgcn_s_setprio(0);
      __builtin_amdgcn_s_barrier();
    }
    // tile boundary: next tile's stages (issued 4 phases ago) must have landed
    asm volatile("s_waitcnt vmcnt(0)" ::: "memory");
    __builtin_amdgcn_sched_barrier(0);
    __builtin_amdgcn_s_barrier();
    __builtin_amdgcn_sched_barrier(0);
  }
#undef STAGE_TILE

  // ---- epilogue: D row = (lane>>4)*4+j (+16*mi), col = lane&15 (+16*n) ----
  const float* brow = bias + (size_t)e * Ndim;
  const int orow0 = row0 + wm * 128 + (lane >> 4) * 4;
  const int ocol0 = col0 + wn * 64 + (lane & 15);
  if (EPI == 0) {
    __hip_bfloat16* H = (__hip_bfloat16*)Cout + (size_t)e * CAP_ * Ndim;
#pragma unroll
    for (int mi = 0; mi < 8; ++mi)
#pragma unroll
      for (int n = 0; n < 4; ++n) {
        int cc = ocol0 + n * 16;
        float bv = brow[cc];
#pragma unroll
        for (int j = 0; j < 4; ++j) {
          int rr = orow0 + mi * 16 + j;
          H[(size_t)rr * Ndim + cc] = __float2bfloat16(gelu_tanh(acc[mi][n][j] + bv));
        }
      }
  } else {
    float* outp = (float*)Cout;
#pragma unroll
    for (int mi = 0; mi < 8; ++mi)
#pragma unroll
      for (int j = 0; j < 4; ++j) {
        int rr = orow0 + mi * 16 + j;
        int tk = idxl[e * CAP_ + rr];
        if (tk < 0) continue;
        float ww = wl[e * CAP_ + rr];
#pragma unroll
        for (int n = 0; n < 4; ++n) {
          int cc = ocol0 + n * 16;
          unsafeAtomicAdd(&outp[(size_t)tk * C_ + cc], ww * (acc[mi][n][j] + brow[cc]));
        }
      }
  }
}

// ---------------- launch ----------------

extern "C" void kernel_launch(void* const* d_in, const int* in_sizes, int n_in,
                              void* d_out, int out_size, void* d_ws,
                              size_t ws_size, hipStream_t stream) {
  (void)in_sizes; (void)n_in; (void)out_size; (void)ws_size;
  const float* x = (const float*)d_in[0];
  const float* w_gate = (const float*)d_in[1];
  const float* b_gate = (const float*)d_in[2];
  const float* W1 = (const float*)d_in[3];
  const float* b1 = (const float*)d_in[4];
  const float* W2 = (const float*)d_in[5];
  const float* b2 = (const float*)d_in[6];
  float* out = (float*)d_out;

  // Workspace layout (peak ~208.3 MiB):
  //   [0,16)    xb   bf16 [N][C]        (dead after GEMM1)
  //   [16,80)   W1t  bf16 [E][F][C]     (dead after GEMM1)
  //   [0,64)    W2t  bf16 [E][C][F]     (converted after GEMM1, over xb/W1t)
  //   [80,208)  Hb   bf16 [E][CAP][F]
  //   [208,...) meta
  char* p = (char*)d_ws;
  __hip_bfloat16* xb = (__hip_bfloat16*)p;
  __hip_bfloat16* W1t = (__hip_bfloat16*)(p + ((size_t)16 << 20));
  __hip_bfloat16* W2t = (__hip_bfloat16*)p;
  __hip_bfloat16* Hb = (__hip_bfloat16*)(p + ((size_t)80 << 20));
  char* meta = p + ((size_t)208 << 20);
  int* slot_e = (int*)meta;                       // 64 KiB
  float* slot_w = (float*)(meta + (64 << 10));    // 64 KiB
  int* idx_list = (int*)(meta + (128 << 10));     // 64 KiB
  float* w_list = (float*)(meta + (192 << 10));   // 64 KiB
  float* probs_sum = (float*)(meta + (256 << 10));
  __hip_bfloat16* zrow = (__hip_bfloat16*)(meta + (260 << 10));  // 16 KiB zeros

  hipMemsetAsync(idx_list, 0xFF, E_ * CAP_ * sizeof(int), stream);
  hipMemsetAsync(probs_sum, 0, E_ * sizeof(float), stream);
  hipMemsetAsync(zrow, 0, 16 << 10, stream);
  hipMemsetAsync(out, 0, (size_t)N_ * C_ * sizeof(float), stream);

  cvt_x_kernel<<<(N_ * C_ / 4 + 255) / 256, 256, 0, stream>>>(x, xb, N_ * C_ / 4);
  transpose_cvt_kernel<<<dim3(F_ / 32, C_ / 32, E_), 256, 0, stream>>>(W1, W1t, C_, F_);
  gate_kernel<<<N_ / 32, 256, 0, stream>>>(x, w_gate, b_gate, slot_e, slot_w, probs_sum);
  scan_kernel<<<1, 256, 0, stream>>>(slot_e, slot_w, idx_list, w_list, probs_sum,
                                     out + (size_t)N_ * C_);
  gemm256<0, true><<<16 * 8 * E_, 512, 0, stream>>>(
      xb, W1t, idx_list, nullptr, b1, Hb, zrow, F_, C_, 16);
  transpose_cvt_kernel<<<dim3(C_ / 32, F_ / 32, E_), 256, 0, stream>>>(W2, W2t, F_, C_);
  gemm256<1, false><<<4 * 8 * E_, 512, 0, stream>>>(
      Hb, W2t, idx_list, w_list, b2, out, zrow, C_, F_, 4);
}

// Round 8
// 955.381 us; speedup vs baseline: 1.1397x; 1.0236x over previous
//
#include <hip/hip_runtime.h>
#include <hip/hip_bf16.h>
#include <math.h>

// MoE forward: B=4 T=2048 C=1024 F=4096 E=8 K=2, CAPACITY=2048, fp32 in/out.
// R7: gemm256 fixed per R6 counters: (a) full 3-bit LDS XOR swizzle
// (slot ^= row&7 on 128B rows; source pre-permuted, lane-linear gload dest),
// (b) counted vmcnt pipeline: B0-3,A0,A2,A1,A3 issue order; vmcnt(2) at tile
// boundary (gates B+A02), vmcnt(8) at phase-1 end (gates A13, keeps next
// tile's 8 loads in flight). 2 barriers/phase, setprio around MFMA.

#define DEV __device__ __forceinline__

typedef __attribute__((ext_vector_type(4))) float f32x4;
typedef __attribute__((ext_vector_type(8))) short bf16x8;

constexpr int B_ = 4, T_ = 2048, C_ = 1024, F_ = 4096, E_ = 8, TOPK_ = 2;
constexpr int N_ = B_ * T_;       // 8192 tokens
constexpr int S_ = N_ * TOPK_;    // 16384 slots
constexpr int CAP_ = 2048;

#define GLOAD16(G, L)                                              \
  __builtin_amdgcn_global_load_lds(                                \
      (const __attribute__((address_space(1))) void*)(G),          \
      (__attribute__((address_space(3))) void*)(L), 16, 0, 0)

DEV float gelu_tanh(float x) {
  float x3 = x * x * x;
  float u = 0.7978845608028654f * (x + 0.044715f * x3);
  return 0.5f * x * (1.0f + tanhf(u));
}

// ---------------- conversion kernels ----------------

__global__ __launch_bounds__(256) void cvt_x_kernel(
    const float* __restrict__ in, __hip_bfloat16* __restrict__ out, int n4) {
  int i = blockIdx.x * 256 + threadIdx.x;
  if (i >= n4) return;
  float4 v = ((const float4*)in)[i];
  __hip_bfloat16 o[4] = {__float2bfloat16(v.x), __float2bfloat16(v.y),
                         __float2bfloat16(v.z), __float2bfloat16(v.w)};
  *(uint2*)(out + (size_t)i * 4) = *(uint2*)o;
}

// in: fp32 [E][R][S] -> out: bf16 [E][S][R]
__global__ __launch_bounds__(256) void transpose_cvt_kernel(
    const float* __restrict__ in, __hip_bfloat16* __restrict__ out, int R, int S) {
  __shared__ float tile[32][33];
  int e = blockIdx.z;
  int s0 = blockIdx.x * 32;
  int r0 = blockIdx.y * 32;
  int tx = threadIdx.x & 31;
  int ty = threadIdx.x >> 5;  // 0..7
  const float* ip = in + (size_t)e * R * S;
  __hip_bfloat16* op = out + (size_t)e * R * S;
#pragma unroll
  for (int i = 0; i < 32; i += 8)
    tile[ty + i][tx] = ip[(size_t)(r0 + ty + i) * S + s0 + tx];
  __syncthreads();
#pragma unroll
  for (int i = 0; i < 32; i += 8)
    op[(size_t)(s0 + ty + i) * R + r0 + tx] = __float2bfloat16(tile[tx][ty + i]);
}

// ---------------- gating ----------------

__global__ __launch_bounds__(256) void gate_kernel(
    const float* __restrict__ x, const float* __restrict__ wg,
    const float* __restrict__ bg, int* __restrict__ slot_e,
    float* __restrict__ slot_w, float* __restrict__ probs_sum) {
  int lane = threadIdx.x & 63;
  int wv = threadIdx.x >> 6;
  int wid = blockIdx.x * 4 + wv;  // 0..1023, 8 tokens each
  float psum[E_];
#pragma unroll
  for (int e = 0; e < E_; ++e) psum[e] = 0.f;

  for (int ti = 0; ti < 8; ++ti) {
    int t = wid * 8 + ti;
    const float* xr = x + (size_t)t * C_;
    float acc[E_];
#pragma unroll
    for (int e = 0; e < E_; ++e) acc[e] = 0.f;
    for (int c = lane; c < C_; c += 64) {
      float xv = xr[c];
      const float* wr = wg + (size_t)c * E_;
#pragma unroll
      for (int e = 0; e < E_; ++e) acc[e] += xv * wr[e];
    }
#pragma unroll
    for (int e = 0; e < E_; ++e) {
#pragma unroll
      for (int off = 32; off >= 1; off >>= 1)
        acc[e] += __shfl_xor(acc[e], off, 64);
    }
    if (lane == 0) {
      float lg[E_], p[E_];
      float mx = -1e30f;
#pragma unroll
      for (int e = 0; e < E_; ++e) { lg[e] = acc[e] + bg[e]; mx = fmaxf(mx, lg[e]); }
      float s = 0.f;
#pragma unroll
      for (int e = 0; e < E_; ++e) { p[e] = expf(lg[e] - mx); s += p[e]; }
      float inv = 1.f / s;
#pragma unroll
      for (int e = 0; e < E_; ++e) { p[e] *= inv; psum[e] += p[e]; }
      int i1 = 0; float p1 = p[0];
#pragma unroll
      for (int e = 1; e < E_; ++e) if (p[e] > p1) { p1 = p[e]; i1 = e; }
      int i2 = -1; float p2 = -1.f;
#pragma unroll
      for (int e = 0; e < E_; ++e) if (e != i1 && p[e] > p2) { p2 = p[e]; i2 = e; }
      float wden = 1.f / (p1 + p2 + 1e-9f);
      slot_e[2 * t] = i1;     slot_w[2 * t] = p1 * wden;
      slot_e[2 * t + 1] = i2; slot_w[2 * t + 1] = p2 * wden;
    }
  }
  if (lane == 0) {
#pragma unroll
    for (int e = 0; e < E_; ++e) atomicAdd(&probs_sum[e], psum[e]);
  }
}

// ---------------- FCFS capacity scan (single block, exact slot order) -------

__global__ __launch_bounds__(256) void scan_kernel(
    const int* __restrict__ slot_e, const float* __restrict__ slot_w,
    int* __restrict__ idx_list, float* __restrict__ w_list,
    const float* __restrict__ probs_sum, float* __restrict__ aux_out) {
  __shared__ int sc[256][E_];
  int tid = threadIdx.x;
  int s0 = tid * 64;
  int cnt[E_];
#pragma unroll
  for (int e = 0; e < E_; ++e) cnt[e] = 0;
  for (int j = 0; j < 64; ++j) cnt[slot_e[s0 + j]]++;
#pragma unroll
  for (int e = 0; e < E_; ++e) sc[tid][e] = cnt[e];
  __syncthreads();
  for (int off = 1; off < 256; off <<= 1) {
    int v[E_];
    bool act = (tid >= off);
    if (act) {
#pragma unroll
      for (int e = 0; e < E_; ++e) v[e] = sc[tid - off][e];
    }
    __syncthreads();
    if (act) {
#pragma unroll
      for (int e = 0; e < E_; ++e) sc[tid][e] += v[e];
    }
    __syncthreads();
  }
  int base[E_];
#pragma unroll
  for (int e = 0; e < E_; ++e) base[e] = tid ? sc[tid - 1][e] : 0;
  for (int j = 0; j < 64; ++j) {
    int s = s0 + j;
    int e = slot_e[s];
    int p = base[e]++;
    if (p < CAP_) {
      idx_list[e * CAP_ + p] = s >> 1;       // token index
      w_list[e * CAP_ + p] = slot_w[s];      // combine weight
    }
  }
  if (tid == 0) {
    float fe[E_], fa[E_], fs = 0.f, ls = 0.f;
#pragma unroll
    for (int e = 0; e < E_; ++e) {
      fe[e] = probs_sum[e] / (float)N_;
      fs += fe[e];
      int tot = sc[255][e];
      fa[e] = (float)(tot < CAP_ ? tot : CAP_);
      ls += fa[e];
    }
    float i1 = 1.f / (fs + 1e-9f), i2 = 1.f / (ls + 1e-9f);
    float a = 0.f;
#pragma unroll
    for (int e = 0; e < E_; ++e) {
      float d = fe[e] * i1 - fa[e] * i2;
      a += d * d;
    }
    aux_out[0] = 0.01f * a / (float)E_;
  }
}

// ---------------- 256x256 4-phase MFMA GEMM (R7 schedule) ------------------
// 512 threads = 8 waves (2M x 4N); per-wave C = 128x64 (acc[8][4] f32x4).
// LDS [2 buf][A,B][256 rows][64 k] bf16 = 128 KiB. Full 3-bit swizzle:
// 16B slot s at row r holds global slot s^(r&7); reads XOR (lane&7)<<4
// (fragment rows always have row&7 == lane&7). Staging source permuted
// ((lane&7)^(lane>>3)), gload dest lane-linear (rule #21).
// Pipeline: STAGE(t+1) issued at phase0 of t (order B0..3,A0,A2,A1,A3);
// phase1-end: vmcnt(8) gates own A1,A3 (next tile's 8 stay in flight);
// phase3-end: vmcnt(2) gates next tile's B+A0,A2. Never drains to 0 mid-loop.

template <int EPI, bool GATHER>
__global__ __launch_bounds__(512, 2) void gemm256(
    const __hip_bfloat16* __restrict__ Aall,
    const __hip_bfloat16* __restrict__ Ball,
    const int* __restrict__ idxl,
    const float* __restrict__ wl,
    const float* __restrict__ bias,
    void* __restrict__ Cout,
    const __hip_bfloat16* __restrict__ zrow,
    int Ndim, int Kdim, int ncol) {
  __shared__ __align__(16) __hip_bfloat16 lds[2][2][256 * 64];  // 128 KiB

  // T1: bijective XCD chunking (gridDim.x % 8 == 0); y innermost so the 8
  // row-blocks sharing a B col-panel land on one XCD.
  const int nwg = gridDim.x;
  const int wg = ((int)blockIdx.x & 7) * (nwg >> 3) + ((int)blockIdx.x >> 3);
  const int e = wg / (ncol * 8);
  const int rem = wg - e * (ncol * 8);
  const int x = rem >> 3, y = rem & 7;
  const int row0 = y * 256, col0 = x * 256;

  const int tid = threadIdx.x;
  const int lane = tid & 63;
  const int w = tid >> 6;           // 0..7
  const int wm = w >> 2, wn = w & 3;

  // ---- staging: 4 chunks x 64 rows; thread -> row rch of each chunk,
  // source col pre-permuted so lane-linear LDS holds the swizzled layout.
  const int rch = w * 8 + (lane >> 3);
  const int cbe = ((lane & 7) ^ (lane >> 3)) << 3;  // elems (16B units)
  const __hip_bfloat16* srcA[4];
  const __hip_bfloat16* srcB[4];
  const __hip_bfloat16* Be = Ball + (size_t)e * Ndim * Kdim;
#pragma unroll
  for (int c = 0; c < 4; ++c) {
    int r = c * 64 + rch;
    if (GATHER) {
      int tok = idxl[e * CAP_ + row0 + r];
      srcA[c] = ((tok >= 0) ? Aall + (size_t)tok * Kdim : zrow) + cbe;
    } else {
      srcA[c] = Aall + ((size_t)e * CAP_ + row0 + r) * Kdim + cbe;
    }
    srcB[c] = Be + (size_t)(col0 + r) * Kdim + cbe;
  }
  const int dstoff = w * 512;  // elems; chunk c adds c*4096 (HW adds lane*16B)

  // ---- fragment geometry (16x16x32: row=lane&15, k=(lane>>4)*8+i) ----
  const int sxor = (lane & 7) << 4;   // 3-bit slot swizzle
  const int rA = wm * 128 + (lane & 15);
  const int rB = wn * 64 + (lane & 15);
  const int kb = (lane >> 4) * 16;    // k-bytes within 64-k row

  f32x4 acc[8][4];
#pragma unroll
  for (int i = 0; i < 8; ++i)
#pragma unroll
    for (int j = 0; j < 4; ++j) acc[i][j] = (f32x4){0.f, 0.f, 0.f, 0.f};

  const int NT = Kdim >> 6;

#define STAGE(PAR, T)                                             \
  {                                                               \
    const int k0_ = (T) * 64;                                     \
    GLOAD16(srcB[0] + k0_, &lds[PAR][1][0 * 4096 + dstoff]);      \
    GLOAD16(srcB[1] + k0_, &lds[PAR][1][1 * 4096 + dstoff]);      \
    GLOAD16(srcB[2] + k0_, &lds[PAR][1][2 * 4096 + dstoff]);      \
    GLOAD16(srcB[3] + k0_, &lds[PAR][1][3 * 4096 + dstoff]);      \
    GLOAD16(srcA[0] + k0_, &lds[PAR][0][0 * 4096 + dstoff]);      \
    GLOAD16(srcA[2] + k0_, &lds[PAR][0][2 * 4096 + dstoff]);      \
    GLOAD16(srcA[1] + k0_, &lds[PAR][0][1 * 4096 + dstoff]);      \
    GLOAD16(srcA[3] + k0_, &lds[PAR][0][3 * 4096 + dstoff]);      \
  }

#define PHASE_READ(Q)                                                       \
  _Pragma("unroll") for (int i = 0; i < 2; ++i)                             \
      _Pragma("unroll") for (int ks = 0; ks < 2; ++ks)                      \
          af[i][ks] = *(const bf16x8*)(baseA +                              \
              ((((rA + ((Q)*2 + i) * 16) * 128) + ks * 64 + kb) ^ sxor));

#define PHASE_MFMA(Q)                                                       \
  __builtin_amdgcn_s_barrier();                                             \
  __builtin_amdgcn_s_setprio(1);                                            \
  _Pragma("unroll") for (int ks = 0; ks < 2; ++ks)                          \
      _Pragma("unroll") for (int i = 0; i < 2; ++i)                         \
          _Pragma("unroll") for (int n = 0; n < 4; ++n)                     \
              acc[(Q)*2 + i][n] = __builtin_amdgcn_mfma_f32_16x16x32_bf16(  \
                  af[i][ks], bfr[n][ks], acc[(Q)*2 + i][n], 0, 0, 0);       \
  __builtin_amdgcn_s_setprio(0);

  STAGE(0, 0);
  asm volatile("s_waitcnt vmcnt(0)" ::: "memory");
  __builtin_amdgcn_sched_barrier(0);
  __builtin_amdgcn_s_barrier();

  for (int t = 0; t < NT; ++t) {
    const int par = t & 1;
    const bool pre = (t + 1 < NT);
    const char* baseA = (const char*)&lds[par][0][0];
    const char* baseB = (const char*)&lds[par][1][0];
    bf16x8 bfr[4][2];
    bf16x8 af[2][2];

    // ---- phase 0: stage t+1, read all B + A rows 0-31, MFMA ----
    if (pre) STAGE(par ^ 1, t + 1);
#pragma unroll
    for (int n = 0; n < 4; ++n)
#pragma unroll
      for (int ks = 0; ks < 2; ++ks)
        bfr[n][ks] = *(const bf16x8*)(baseB +
            ((((rB + n * 16) * 128) + ks * 64 + kb) ^ sxor));
    PHASE_READ(0);
    PHASE_MFMA(0);
    __builtin_amdgcn_s_barrier();

    // ---- phase 1: A rows 32-63; end gates own A1,A3 (counted) ----
    PHASE_READ(1);
    PHASE_MFMA(1);
    if (pre) asm volatile("s_waitcnt vmcnt(8)" ::: "memory");
    else     asm volatile("s_waitcnt vmcnt(0)" ::: "memory");
    __builtin_amdgcn_sched_barrier(0);
    __builtin_amdgcn_s_barrier();

    // ---- phase 2: A rows 64-95 ----
    PHASE_READ(2);
    PHASE_MFMA(2);
    __builtin_amdgcn_s_barrier();

    // ---- phase 3: A rows 96-127; end gates next tile's B+A0,A2 ----
    PHASE_READ(3);
    PHASE_MFMA(3);
    asm volatile("s_waitcnt vmcnt(2)" ::: "memory");
    __builtin_amdgcn_sched_barrier(0);
    __builtin_amdgcn_s_barrier();
  }
#undef STAGE
#undef PHASE_READ
#undef PHASE_MFMA

  // ---- epilogue: D row = (lane>>4)*4+j (+16*mi), col = lane&15 (+16*n) ----
  const float* brow = bias + (size_t)e * Ndim;
  const int orow0 = row0 + wm * 128 + (lane >> 4) * 4;
  const int ocol0 = col0 + wn * 64 + (lane & 15);
  if (EPI == 0) {
    __hip_bfloat16* H = (__hip_bfloat16*)Cout + (size_t)e * CAP_ * Ndim;
#pragma unroll
    for (int mi = 0; mi < 8; ++mi)
#pragma unroll
      for (int n = 0; n < 4; ++n) {
        int cc = ocol0 + n * 16;
        float bv = brow[cc];
#pragma unroll
        for (int j = 0; j < 4; ++j) {
          int rr = orow0 + mi * 16 + j;
          H[(size_t)rr * Ndim + cc] = __float2bfloat16(gelu_tanh(acc[mi][n][j] + bv));
        }
      }
  } else {
    float* outp = (float*)Cout;
#pragma unroll
    for (int mi = 0; mi < 8; ++mi)
#pragma unroll
      for (int j = 0; j < 4; ++j) {
        int rr = orow0 + mi * 16 + j;
        int tk = idxl[e * CAP_ + rr];
        if (tk < 0) continue;
        float ww = wl[e * CAP_ + rr];
#pragma unroll
        for (int n = 0; n < 4; ++n) {
          int cc = ocol0 + n * 16;
          unsafeAtomicAdd(&outp[(size_t)tk * C_ + cc], ww * (acc[mi][n][j] + brow[cc]));
        }
      }
  }
}

// ---------------- launch ----------------

extern "C" void kernel_launch(void* const* d_in, const int* in_sizes, int n_in,
                              void* d_out, int out_size, void* d_ws,
                              size_t ws_size, hipStream_t stream) {
  (void)in_sizes; (void)n_in; (void)out_size; (void)ws_size;
  const float* x = (const float*)d_in[0];
  const float* w_gate = (const float*)d_in[1];
  const float* b_gate = (const float*)d_in[2];
  const float* W1 = (const float*)d_in[3];
  const float* b1 = (const float*)d_in[4];
  const float* W2 = (const float*)d_in[5];
  const float* b2 = (const float*)d_in[6];
  float* out = (float*)d_out;

  // Workspace layout (peak ~208.3 MiB):
  //   [0,16)    xb   bf16 [N][C]        (dead after GEMM1)
  //   [16,80)   W1t  bf16 [E][F][C]     (dead after GEMM1)
  //   [0,64)    W2t  bf16 [E][C][F]     (converted after GEMM1, over xb/W1t)
  //   [80,208)  Hb   bf16 [E][CAP][F]
  //   [208,...) meta
  char* p = (char*)d_ws;
  __hip_bfloat16* xb = (__hip_bfloat16*)p;
  __hip_bfloat16* W1t = (__hip_bfloat16*)(p + ((size_t)16 << 20));
  __hip_bfloat16* W2t = (__hip_bfloat16*)p;
  __hip_bfloat16* Hb = (__hip_bfloat16*)(p + ((size_t)80 << 20));
  char* meta = p + ((size_t)208 << 20);
  int* slot_e = (int*)meta;                       // 64 KiB
  float* slot_w = (float*)(meta + (64 << 10));    // 64 KiB
  int* idx_list = (int*)(meta + (128 << 10));     // 64 KiB
  float* w_list = (float*)(meta + (192 << 10));   // 64 KiB
  float* probs_sum = (float*)(meta + (256 << 10));
  __hip_bfloat16* zrow = (__hip_bfloat16*)(meta + (260 << 10));  // 16 KiB zeros

  hipMemsetAsync(idx_list, 0xFF, E_ * CAP_ * sizeof(int), stream);
  hipMemsetAsync(probs_sum, 0, E_ * sizeof(float), stream);
  hipMemsetAsync(zrow, 0, 16 << 10, stream);
  hipMemsetAsync(out, 0, (size_t)N_ * C_ * sizeof(float), stream);

  cvt_x_kernel<<<(N_ * C_ / 4 + 255) / 256, 256, 0, stream>>>(x, xb, N_ * C_ / 4);
  transpose_cvt_kernel<<<dim3(F_ / 32, C_ / 32, E_), 256, 0, stream>>>(W1, W1t, C_, F_);
  gate_kernel<<<N_ / 32, 256, 0, stream>>>(x, w_gate, b_gate, slot_e, slot_w, probs_sum);
  scan_kernel<<<1, 256, 0, stream>>>(slot_e, slot_w, idx_list, w_list, probs_sum,
                                     out + (size_t)N_ * C_);
  gemm256<0, true><<<16 * 8 * E_, 512, 0, stream>>>(
      xb, W1t, idx_list, nullptr, b1, Hb, zrow, F_, C_, 16);
  transpose_cvt_kernel<<<dim3(C_ / 32, F_ / 32, E_), 256, 0, stream>>>(W2, W2t, F_, C_);
  gemm256<1, false><<<4 * 8 * E_, 512, 0, stream>>>(
      Hb, W2t, idx_list, w_list, b2, out, zrow, C_, F_, 4);
}

// Round 10
// 895.834 us; speedup vs baseline: 1.2155x; 1.0665x over previous
//
#include <hip/hip_runtime.h>
#include <hip/hip_bf16.h>
#include <math.h>

// MoE forward: B=4 T=2048 C=1024 F=4096 E=8 K=2, CAPACITY=2048, fp32 in/out.
// R9: (1) fast 64x64 transpose_cvt (float4/ushort4, conflict-free LDS);
// (2) GEMM 256x128 / BK=32 / 3-buffer LDS ring (72KiB -> 2 blocks/CU) /
// 2-deep prefetch, steady vmcnt(3), 1 barrier/tile, swizzled LDS (0-conflict);
// (3) gelu via sigma(2u) with __expf. Atomic combine epilogue unchanged.

#define DEV __device__ __forceinline__

typedef __attribute__((ext_vector_type(4))) float f32x4;
typedef __attribute__((ext_vector_type(8))) short bf16x8;

constexpr int B_ = 4, T_ = 2048, C_ = 1024, F_ = 4096, E_ = 8, TOPK_ = 2;
constexpr int N_ = B_ * T_;       // 8192 tokens
constexpr int S_ = N_ * TOPK_;    // 16384 slots
constexpr int CAP_ = 2048;

#define GLOAD16(G, L)                                              \
  __builtin_amdgcn_global_load_lds(                                \
      (const __attribute__((address_space(1))) void*)(G),          \
      (__attribute__((address_space(3))) void*)(L), 16, 0, 0)

DEV float gelu_tanh(float x) {
  // 0.5x(1+tanh(u)) == x * sigmoid(2u), u = 0.7978845608(x + 0.044715 x^3)
  float u = 0.7978845608028654f * (x + 0.044715f * x * x * x);
  return x / (1.0f + __expf(-2.0f * u));
}

// ---------------- conversion kernels ----------------

__global__ __launch_bounds__(256) void cvt_x_kernel(
    const float* __restrict__ in, __hip_bfloat16* __restrict__ out, int n4) {
  int i = blockIdx.x * 256 + threadIdx.x;
  if (i >= n4) return;
  float4 v = ((const float4*)in)[i];
  __hip_bfloat16 o[4] = {__float2bfloat16(v.x), __float2bfloat16(v.y),
                         __float2bfloat16(v.z), __float2bfloat16(v.w)};
  *(uint2*)(out + (size_t)i * 4) = *(uint2*)o;
}

// in: fp32 [E][R][S] -> out: bf16 [E][S][R]; 64x64 tiles.
__global__ __launch_bounds__(256) void transpose_cvt_kernel(
    const float* __restrict__ in, __hip_bfloat16* __restrict__ out, int R, int S) {
  __shared__ float tile[64][65];
  const int e = blockIdx.z;
  const int s0 = blockIdx.x * 64;
  const int r0 = blockIdx.y * 64;
  const int tx = threadIdx.x & 15;
  const int ty = threadIdx.x >> 4;  // 0..15
  const float* ip = in + (size_t)e * R * S;
  __hip_bfloat16* op = out + (size_t)e * R * S;
#pragma unroll
  for (int it = 0; it < 4; ++it) {
    int r = ty + it * 16;
    float4 v = *(const float4*)&ip[(size_t)(r0 + r) * S + s0 + tx * 4];
    tile[r][tx * 4 + 0] = v.x;
    tile[r][tx * 4 + 1] = v.y;
    tile[r][tx * 4 + 2] = v.z;
    tile[r][tx * 4 + 3] = v.w;
  }
  __syncthreads();
#pragma unroll
  for (int it = 0; it < 4; ++it) {
    int sr = ty + it * 16;
    ushort o[4];
#pragma unroll
    for (int j = 0; j < 4; ++j) {
      union { __hip_bfloat16 b; ushort u; } cv;
      cv.b = __float2bfloat16(tile[tx * 4 + j][sr]);
      o[j] = cv.u;
    }
    *(ushort4*)&op[(size_t)(s0 + sr) * R + r0 + tx * 4] = *(ushort4*)o;
  }
}

// ---------------- gating ----------------

__global__ __launch_bounds__(256) void gate_kernel(
    const float* __restrict__ x, const float* __restrict__ wg,
    const float* __restrict__ bg, int* __restrict__ slot_e,
    float* __restrict__ slot_w, float* __restrict__ probs_sum) {
  int lane = threadIdx.x & 63;
  int wv = threadIdx.x >> 6;
  int wid = blockIdx.x * 4 + wv;  // 0..1023, 8 tokens each
  float psum[E_];
#pragma unroll
  for (int e = 0; e < E_; ++e) psum[e] = 0.f;

  for (int ti = 0; ti < 8; ++ti) {
    int t = wid * 8 + ti;
    const float* xr = x + (size_t)t * C_;
    float acc[E_];
#pragma unroll
    for (int e = 0; e < E_; ++e) acc[e] = 0.f;
    for (int c = lane; c < C_; c += 64) {
      float xv = xr[c];
      const float* wr = wg + (size_t)c * E_;
#pragma unroll
      for (int e = 0; e < E_; ++e) acc[e] += xv * wr[e];
    }
#pragma unroll
    for (int e = 0; e < E_; ++e) {
#pragma unroll
      for (int off = 32; off >= 1; off >>= 1)
        acc[e] += __shfl_xor(acc[e], off, 64);
    }
    if (lane == 0) {
      float lg[E_], p[E_];
      float mx = -1e30f;
#pragma unroll
      for (int e = 0; e < E_; ++e) { lg[e] = acc[e] + bg[e]; mx = fmaxf(mx, lg[e]); }
      float s = 0.f;
#pragma unroll
      for (int e = 0; e < E_; ++e) { p[e] = expf(lg[e] - mx); s += p[e]; }
      float inv = 1.f / s;
#pragma unroll
      for (int e = 0; e < E_; ++e) { p[e] *= inv; psum[e] += p[e]; }
      int i1 = 0; float p1 = p[0];
#pragma unroll
      for (int e = 1; e < E_; ++e) if (p[e] > p1) { p1 = p[e]; i1 = e; }
      int i2 = -1; float p2 = -1.f;
#pragma unroll
      for (int e = 0; e < E_; ++e) if (e != i1 && p[e] > p2) { p2 = p[e]; i2 = e; }
      float wden = 1.f / (p1 + p2 + 1e-9f);
      slot_e[2 * t] = i1;     slot_w[2 * t] = p1 * wden;
      slot_e[2 * t + 1] = i2; slot_w[2 * t + 1] = p2 * wden;
    }
  }
  if (lane == 0) {
#pragma unroll
    for (int e = 0; e < E_; ++e) atomicAdd(&probs_sum[e], psum[e]);
  }
}

// ---------------- FCFS capacity scan (single block, exact slot order) -------

__global__ __launch_bounds__(256) void scan_kernel(
    const int* __restrict__ slot_e, const float* __restrict__ slot_w,
    int* __restrict__ idx_list, float* __restrict__ w_list,
    const float* __restrict__ probs_sum, float* __restrict__ aux_out) {
  __shared__ int sc[256][E_];
  int tid = threadIdx.x;
  int s0 = tid * 64;
  int cnt[E_];
#pragma unroll
  for (int e = 0; e < E_; ++e) cnt[e] = 0;
  for (int j = 0; j < 64; ++j) cnt[slot_e[s0 + j]]++;
#pragma unroll
  for (int e = 0; e < E_; ++e) sc[tid][e] = cnt[e];
  __syncthreads();
  for (int off = 1; off < 256; off <<= 1) {
    int v[E_];
    bool act = (tid >= off);
    if (act) {
#pragma unroll
      for (int e = 0; e < E_; ++e) v[e] = sc[tid - off][e];
    }
    __syncthreads();
    if (act) {
#pragma unroll
      for (int e = 0; e < E_; ++e) sc[tid][e] += v[e];
    }
    __syncthreads();
  }
  int base[E_];
#pragma unroll
  for (int e = 0; e < E_; ++e) base[e] = tid ? sc[tid - 1][e] : 0;
  for (int j = 0; j < 64; ++j) {
    int s = s0 + j;
    int e = slot_e[s];
    int p = base[e]++;
    if (p < CAP_) {
      idx_list[e * CAP_ + p] = s >> 1;       // token index
      w_list[e * CAP_ + p] = slot_w[s];      // combine weight
    }
  }
  if (tid == 0) {
    float fe[E_], fa[E_], fs = 0.f, ls = 0.f;
#pragma unroll
    for (int e = 0; e < E_; ++e) {
      fe[e] = probs_sum[e] / (float)N_;
      fs += fe[e];
      int tot = sc[255][e];
      fa[e] = (float)(tot < CAP_ ? tot : CAP_);
      ls += fa[e];
    }
    float i1 = 1.f / (fs + 1e-9f), i2 = 1.f / (ls + 1e-9f);
    float a = 0.f;
#pragma unroll
    for (int e = 0; e < E_; ++e) {
      float d = fe[e] * i1 - fa[e] * i2;
      a += d * d;
    }
    aux_out[0] = 0.01f * a / (float)E_;
  }
}

// ---------------- 256x128 MFMA GEMM, BK=32, 3-buffer ring ------------------
// 512 thr = 8 waves (4M x 2N), per-wave C = 64x64 (acc[4][4]).
// LDS: 3 bufs x (A[256][32] + B[128][32]) bf16 = 72 KiB -> 2 blocks/CU.
// Rows are 64B = 4 x 16B slots; swizzle: stored slot = global slot ^ ((row>>1)&3).
// Stage: lane-linear dest; source col pre-permuted (rule #21).
// Pipeline: 2-deep prefetch, per tile {STAGE(t+2); 4 B + 4 A ds_read; 16 MFMA;
// vmcnt(3); barrier} -- vmcnt never drains to 0 mid-loop (T4).
// EPI 0: gelu(acc+bias)->bf16 H ; EPI 1: atomic scatter w*(acc+bias) to out.

template <int EPI, bool GATHER>
__global__ __launch_bounds__(512, 4) void gemm256(
    const __hip_bfloat16* __restrict__ Aall,
    const __hip_bfloat16* __restrict__ Ball,
    const int* __restrict__ idxl,
    const float* __restrict__ wl,
    const float* __restrict__ bias,
    void* __restrict__ Cout,
    const __hip_bfloat16* __restrict__ zrow,
    int Ndim, int Kdim, int ncol) {
  __shared__ __align__(16) __hip_bfloat16 lds[3][12288];  // per buf: A 8192, B 4096 elems

  // T1: bijective XCD chunking (gridDim.x % 8 == 0); y innermost: the 8
  // row-blocks sharing a B col-panel land on one XCD.
  const int nwg = gridDim.x;
  const int wg = ((int)blockIdx.x & 7) * (nwg >> 3) + ((int)blockIdx.x >> 3);
  const int e = wg / (ncol * 8);
  const int rem = wg - e * (ncol * 8);
  const int x = rem >> 3, y = rem & 7;
  const int row0 = y * 256, col0 = x * 128;

  const int tid = threadIdx.x;
  const int l = tid & 63;
  const int w = tid >> 6;           // 0..7
  const int wm = w >> 1, wn = w & 1;

  // ---- staging geometry: thread covers row rst (of 128) at swizzled col ----
  const int rst = w * 16 + (l >> 2);                    // 0..127
  const int colel = (((l & 3) ^ ((l >> 3) & 3)) << 3);  // source col elems
  const __hip_bfloat16* Be = Ball + (size_t)e * Ndim * Kdim;
  const __hip_bfloat16 *pA0, *pA1, *pB;
  if (GATHER) {
    int t0 = idxl[e * CAP_ + row0 + rst];
    int t1 = idxl[e * CAP_ + row0 + 128 + rst];
    pA0 = ((t0 >= 0) ? Aall + (size_t)t0 * Kdim : zrow) + colel;
    pA1 = ((t1 >= 0) ? Aall + (size_t)t1 * Kdim : zrow) + colel;
  } else {
    pA0 = Aall + ((size_t)e * CAP_ + row0 + rst) * Kdim + colel;
    pA1 = Aall + ((size_t)e * CAP_ + row0 + 128 + rst) * Kdim + colel;
  }
  pB = Be + (size_t)(col0 + rst) * Kdim + colel;
  const int dA0 = w * 512;           // elems (HW adds lane*16B)
  const int dA1 = 4096 + w * 512;
  const int dB = 8192 + w * 512;

  // ---- fragment read geometry ----
  // byte offset within A/B block: row*64 + 16*((l>>4) ^ ((l>>1)&3)) + row_base*64
  const int loff = (l & 15) * 64 + ((((l >> 4) ^ ((l >> 1) & 3))) << 4);
  const int rAoff = (wm * 64) * 64 + loff;           // A rows wm*64..+63
  const int rBoff = 8192 * 2 + (wn * 64) * 64 + loff;  // B rows wn*64..+63 (bytes)

  f32x4 acc[4][4];
#pragma unroll
  for (int i = 0; i < 4; ++i)
#pragma unroll
    for (int j = 0; j < 4; ++j) acc[i][j] = (f32x4){0.f, 0.f, 0.f, 0.f};

  const int NT = Kdim >> 5;

#define STAGE(BUF)                                   \
  {                                                  \
    GLOAD16(pB, &lds[BUF][dB]);                      \
    GLOAD16(pA0, &lds[BUF][dA0]);                    \
    GLOAD16(pA1, &lds[BUF][dA1]);                    \
    pA0 += 32; pA1 += 32; pB += 32;                  \
  }

  STAGE(0);
  STAGE(1);
  asm volatile("s_waitcnt vmcnt(3)" ::: "memory");
  __builtin_amdgcn_sched_barrier(0);
  __builtin_amdgcn_s_barrier();

  int par = 0;
  for (int t = 0; t < NT; ++t) {
    const bool pre = (t + 2 < NT);
    const int stg = (par + 2 >= 3) ? par - 1 : par + 2;
    if (pre) STAGE(stg);
    const char* base = (const char*)&lds[par][0];
    bf16x8 bf[4], af[4];
#pragma unroll
    for (int ni = 0; ni < 4; ++ni)
      bf[ni] = *(const bf16x8*)(base + rBoff + ni * 1024);
#pragma unroll
    for (int mi = 0; mi < 4; ++mi)
      af[mi] = *(const bf16x8*)(base + rAoff + mi * 1024);
    __builtin_amdgcn_s_setprio(1);
#pragma unroll
    for (int mi = 0; mi < 4; ++mi)
#pragma unroll
      for (int ni = 0; ni < 4; ++ni)
        acc[mi][ni] = __builtin_amdgcn_mfma_f32_16x16x32_bf16(
            af[mi], bf[ni], acc[mi][ni], 0, 0, 0);
    __builtin_amdgcn_s_setprio(0);
    if (pre) asm volatile("s_waitcnt vmcnt(3)" ::: "memory");
    else     asm volatile("s_waitcnt vmcnt(0)" ::: "memory");
    __builtin_amdgcn_sched_barrier(0);
    __builtin_amdgcn_s_barrier();
    par = (par + 1 >= 3) ? 0 : par + 1;
  }
#undef STAGE

  // ---- epilogue: D row = (lane>>4)*4+j (+16*mi), col = lane&15 (+16*ni) ----
  const float* brow = bias + (size_t)e * Ndim;
  const int orow0 = row0 + wm * 64 + (l >> 4) * 4;
  const int ocol0 = col0 + wn * 64 + (l & 15);
  if (EPI == 0) {
    __hip_bfloat16* H = (__hip_bfloat16*)Cout + (size_t)e * CAP_ * Ndim;
#pragma unroll
    for (int mi = 0; mi < 4; ++mi)
#pragma unroll
      for (int ni = 0; ni < 4; ++ni) {
        int cc = ocol0 + ni * 16;
        float bv = brow[cc];
#pragma unroll
        for (int j = 0; j < 4; ++j) {
          int rr = orow0 + mi * 16 + j;
          H[(size_t)rr * Ndim + cc] = __float2bfloat16(gelu_tanh(acc[mi][ni][j] + bv));
        }
      }
  } else {
    float* outp = (float*)Cout;
#pragma unroll
    for (int mi = 0; mi < 4; ++mi)
#pragma unroll
      for (int j = 0; j < 4; ++j) {
        int rr = orow0 + mi * 16 + j;
        int tk = idxl[e * CAP_ + rr];
        if (tk < 0) continue;
        float ww = wl[e * CAP_ + rr];
#pragma unroll
        for (int ni = 0; ni < 4; ++ni) {
          int cc = ocol0 + ni * 16;
          unsafeAtomicAdd(&outp[(size_t)tk * C_ + cc], ww * (acc[mi][ni][j] + brow[cc]));
        }
      }
  }
}

// ---------------- launch ----------------

extern "C" void kernel_launch(void* const* d_in, const int* in_sizes, int n_in,
                              void* d_out, int out_size, void* d_ws,
                              size_t ws_size, hipStream_t stream) {
  (void)in_sizes; (void)n_in; (void)out_size; (void)ws_size;
  const float* x = (const float*)d_in[0];
  const float* w_gate = (const float*)d_in[1];
  const float* b_gate = (const float*)d_in[2];
  const float* W1 = (const float*)d_in[3];
  const float* b1 = (const float*)d_in[4];
  const float* W2 = (const float*)d_in[5];
  const float* b2 = (const float*)d_in[6];
  float* out = (float*)d_out;

  // Workspace layout (peak ~208.3 MiB):
  //   [0,16)    xb   bf16 [N][C]        (dead after GEMM1)
  //   [16,80)   W1t  bf16 [E][F][C]     (dead after GEMM1)
  //   [0,64)    W2t  bf16 [E][C][F]     (converted after GEMM1, over xb/W1t)
  //   [80,208)  Hb   bf16 [E][CAP][F]
  //   [208,...) meta
  char* p = (char*)d_ws;
  __hip_bfloat16* xb = (__hip_bfloat16*)p;
  __hip_bfloat16* W1t = (__hip_bfloat16*)(p + ((size_t)16 << 20));
  __hip_bfloat16* W2t = (__hip_bfloat16*)p;
  __hip_bfloat16* Hb = (__hip_bfloat16*)(p + ((size_t)80 << 20));
  char* meta = p + ((size_t)208 << 20);
  int* slot_e = (int*)meta;                       // 64 KiB
  float* slot_w = (float*)(meta + (64 << 10));    // 64 KiB
  int* idx_list = (int*)(meta + (128 << 10));     // 64 KiB
  float* w_list = (float*)(meta + (192 << 10));   // 64 KiB
  float* probs_sum = (float*)(meta + (256 << 10));
  __hip_bfloat16* zrow = (__hip_bfloat16*)(meta + (260 << 10));  // 16 KiB zeros

  hipMemsetAsync(idx_list, 0xFF, E_ * CAP_ * sizeof(int), stream);
  hipMemsetAsync(probs_sum, 0, E_ * sizeof(float), stream);
  hipMemsetAsync(zrow, 0, 16 << 10, stream);
  hipMemsetAsync(out, 0, (size_t)N_ * C_ * sizeof(float), stream);

  cvt_x_kernel<<<(N_ * C_ / 4 + 255) / 256, 256, 0, stream>>>(x, xb, N_ * C_ / 4);
  transpose_cvt_kernel<<<dim3(F_ / 64, C_ / 64, E_), 256, 0, stream>>>(W1, W1t, C_, F_);
  gate_kernel<<<N_ / 32, 256, 0, stream>>>(x, w_gate, b_gate, slot_e, slot_w, probs_sum);
  scan_kernel<<<1, 256, 0, stream>>>(slot_e, slot_w, idx_list, w_list, probs_sum,
                                     out + (size_t)N_ * C_);
  // GEMM1: [CAP x F] per expert, K=C. grid = E * (F/128) * (CAP/256) = 2048
  gemm256<0, true><<<E_ * 32 * 8, 512, 0, stream>>>(
      xb, W1t, idx_list, nullptr, b1, Hb, zrow, F_, C_, 32);
  transpose_cvt_kernel<<<dim3(C_ / 64, F_ / 64, E_), 256, 0, stream>>>(W2, W2t, F_, C_);
  // GEMM2: [CAP x C] per expert, K=F. grid = E * (C/128) * (CAP/256) = 512
  gemm256<1, false><<<E_ * 8 * 8, 512, 0, stream>>>(
      Hb, W2t, idx_list, w_list, b2, out, zrow, C_, F_, 8);
}